// Round 16
// baseline (4824.940 us; speedup 1.0000x reference)
//
#include <hip/hip_runtime.h>
#include <stdint.h>
#include <math.h>

// Problem constants (from reference)
constexpr int kB = 8;      // clouds
constexpr int kP = 8192;   // points per cloud
constexpr int kF = 32;     // feature dim
constexpr int kM = 2048;   // centroids per cloud (P * 0.25)
constexpr int kK = 64;     // max neighbors
constexpr int kO = 128;    // output dim

typedef float v2f __attribute__((ext_vector_type(2)));
typedef _Float16 h8 __attribute__((ext_vector_type(8)));
typedef float f4v __attribute__((ext_vector_type(4)));

// Exact-f32 squared distance matching numpy: square elementwise, then
// sequential sum ((dx2+dy2)+dz2). contract(off) forbids fma fusion so this
// matches numpy bit-for-bit regardless of -ffp-contract=fast default.
__device__ __forceinline__ float dist2(float ax, float ay, float az,
                                       float bx, float by, float bz) {
#pragma clang fp contract(off)
    float dx = ax - bx, dy = ay - by, dz = az - bz;
    return (dx * dx + dy * dy) + dz * dz;
}

// One DPP step of a u64 (hi,lo) max-reduce. CTRL must be an immediate ->
// template parameter. bound_ctrl=true: invalid source lanes read 0, and
// (0,0) never wins because all real keys have klo = ~idx != 0.
template <int CTRL>
__device__ __forceinline__ void dpp_max_step(unsigned int& khi, unsigned int& klo) {
    unsigned int ohi = (unsigned int)__builtin_amdgcn_update_dpp(
        0, (int)khi, CTRL, 0xf, 0xf, true);
    unsigned int olo = (unsigned int)__builtin_amdgcn_update_dpp(
        0, (int)klo, CTRL, 0xf, 0xf, true);
    bool take = (ohi > khi) || (ohi == khi && olo > klo);
    khi = take ? ohi : khi;
    klo = take ? olo : klo;
}

// Per-cloud update + wave-reduce, bit-identical to the r14 fps math.
// Emits the thread's wave-level key via DPP; lane 63 holds the wave max.
#define FPS_UPDATE_REDUCE(PX, PY, PZ, DD, LX, LY, LZ, KHI, KLO, WIOUT_UNUSED) \
    {                                                                          \
        v2f lxv = {LX, LX}, lyv = {LY, LY}, lzv = {LZ, LZ};                    \
        _Pragma("unroll")                                                      \
        for (int q = 0; q < 16; ++q) {                                         \
            _Pragma("clang fp contract(off)")                                  \
            v2f dx = PX[q] - lxv;                                              \
            v2f dy = PY[q] - lyv;                                              \
            v2f dz = PZ[q] - lzv;                                              \
            v2f d2 = (dx * dx + dy * dy) + dz * dz;                            \
            DD[q].x = fminf(DD[q].x, d2.x);                                    \
            DD[q].y = fminf(DD[q].y, d2.y);                                    \
        }                                                                      \
        v2f t0 = {fmaxf(DD[0].x, DD[0].y), fmaxf(DD[1].x, DD[1].y)};           \
        v2f t1 = {fmaxf(DD[2].x, DD[2].y), fmaxf(DD[3].x, DD[3].y)};           \
        v2f t2 = {fmaxf(DD[4].x, DD[4].y), fmaxf(DD[5].x, DD[5].y)};           \
        v2f t3 = {fmaxf(DD[6].x, DD[6].y), fmaxf(DD[7].x, DD[7].y)};           \
        v2f t4 = {fmaxf(DD[8].x, DD[8].y), fmaxf(DD[9].x, DD[9].y)};           \
        v2f t5 = {fmaxf(DD[10].x, DD[10].y), fmaxf(DD[11].x, DD[11].y)};       \
        v2f t6 = {fmaxf(DD[12].x, DD[12].y), fmaxf(DD[13].x, DD[13].y)};       \
        v2f t7 = {fmaxf(DD[14].x, DD[14].y), fmaxf(DD[15].x, DD[15].y)};       \
        float u0 = fmaxf(fmaxf(t0.x, t0.y), fmaxf(t1.x, t1.y));                \
        float u1 = fmaxf(fmaxf(t2.x, t2.y), fmaxf(t3.x, t3.y));                \
        float u2 = fmaxf(fmaxf(t4.x, t4.y), fmaxf(t5.x, t5.y));                \
        float u3 = fmaxf(fmaxf(t6.x, t6.y), fmaxf(t7.x, t7.y));                \
        float bv = fmaxf(fmaxf(u0, u1), fmaxf(u2, u3));                        \
        int lqs[4];                                                            \
        _Pragma("unroll")                                                      \
        for (int g = 0; g < 4; ++g) {                                          \
            int t = 64;                                                        \
            _Pragma("unroll")                                                  \
            for (int s = 7; s >= 0; --s) {                                     \
                int sl = g * 8 + s;                                            \
                float v = (sl & 1) ? DD[sl >> 1].y : DD[sl >> 1].x;            \
                t = (v == bv) ? sl : t;                                        \
            }                                                                  \
            lqs[g] = t;                                                        \
        }                                                                      \
        int bq = lqs[3];                                                       \
        bq = (lqs[2] < 64) ? lqs[2] : bq;                                      \
        bq = (lqs[1] < 64) ? lqs[1] : bq;                                      \
        bq = (lqs[0] < 64) ? lqs[0] : bq;                                      \
        unsigned int bidx = (unsigned int)(tid + bq * 256);                    \
        KHI = __float_as_uint(bv);                                             \
        KLO = (unsigned int)(~bidx);                                           \
        dpp_max_step<0x111>(KHI, KLO);                                         \
        dpp_max_step<0x112>(KHI, KLO);                                         \
        dpp_max_step<0x114>(KHI, KLO);                                         \
        dpp_max_step<0x118>(KHI, KLO);                                         \
        dpp_max_step<0x142>(KHI, KLO);                                         \
        dpp_max_step<0x143>(KHI, KLO);                                         \
    }

// Zero the progress flags (d_ws is poisoned 0xAA before every launch).
__global__ void init_kernel(int* __restrict__ prog) {
    if (threadIdx.x < 128) prog[threadIdx.x] = 0;
}

// Role-union LDS. fps: cloud-A coords + winner indices (~104 KB).
// consumer: fp16 MFMA tiles + transposed weights (~121 KB). 1 block/CU.
union SharedU {
    struct {
        float sxp[kP], syp[kP], szp[kP];       // cloud A SoA copy
        unsigned short widxA[kM], widxB[kM];   // winner indices
        unsigned long long partA[2][4];        // ping-pong wave partials
        unsigned long long partB[2][4];
    } f;
    struct {
        _Float16 A0[256][72];                  // msg (cols 0..63), reused as h2
        _Float16 A1[256][72];                  // h1
        _Float16 Wt1[64][72];                  // W1^T [n][k], k>=35 zero
        _Float16 Wt2[64][72];                  // W2^T [n][k]
        _Float16 Wt3[128][72];                 // W3^T [n][k]
        float bias[256];                       // b1 | b2 | b3
        float red[4][4][128];                  // [centroid][quad][col]
        int   s_nb[4][kK];
        int   s_cnt[4];
    } c;
};

// ---------------------------------------------------------------------------
// Mega-kernel, 256 threads/block:
//  blocks 0..3    : FPS for TWO clouds (2f, 2f+1), software-pipelined:
//                   per loop body update+reduce A then B (independent
//                   register state), ONE barrier, then scan B first (its
//                   winner-coord GLOBAL loads hide under A's next update),
//                   scan A (coords from LDS). Each cloud's arithmetic is
//                   instruction-identical to r14 -> bit-exact selection.
//  blocks 4..4099 : r14-proven consumer (4 centroids, fp16 MFMA, fp32 acc).
// ---------------------------------------------------------------------------
__global__ __launch_bounds__(256, 1) void mega_kernel(
    const float* __restrict__ pos, const float* __restrict__ x,
    const float* __restrict__ W1, const float* __restrict__ b1,
    const float* __restrict__ W2, const float* __restrict__ b2,
    const float* __restrict__ W3, const float* __restrict__ b3,
    unsigned int* __restrict__ stage, int* __restrict__ prog,
    float* __restrict__ cent_out, float* __restrict__ feat_out,
    float* __restrict__ batch_out) {
    __shared__ SharedU sh;

    const int tid = threadIdx.x;
    const int wave = tid >> 6, lane = tid & 63;

    if (blockIdx.x < 4u) {
        // ======================= FPS role: clouds bA, bB ===================
        const int bA = (int)blockIdx.x * 2, bB = bA + 1;
        const float* pA = pos + (size_t)bA * kP * 3;
        const float* pB = pos + (size_t)bB * kP * 3;

        v2f pxA[16], pyA[16], pzA[16], ddA[16];
        v2f pxB[16], pyB[16], pzB[16], ddB[16];
#pragma unroll
        for (int q = 0; q < 32; ++q) {
            int i = tid + q * 256;
            float XA = pA[i * 3 + 0], YA = pA[i * 3 + 1], ZA = pA[i * 3 + 2];
            sh.f.sxp[i] = XA; sh.f.syp[i] = YA; sh.f.szp[i] = ZA;
            float XB = pB[i * 3 + 0], YB = pB[i * 3 + 1], ZB = pB[i * 3 + 2];
            if (q & 1) {
                pxA[q >> 1].y = XA; pyA[q >> 1].y = YA; pzA[q >> 1].y = ZA;
                pxB[q >> 1].y = XB; pyB[q >> 1].y = YB; pzB[q >> 1].y = ZB;
            } else {
                pxA[q >> 1].x = XA; pyA[q >> 1].x = YA; pzA[q >> 1].x = ZA;
                pxB[q >> 1].x = XB; pyB[q >> 1].x = YB; pzB[q >> 1].x = ZB;
            }
        }
#pragma unroll
        for (int q = 0; q < 16; ++q) {
            ddA[q] = (v2f){INFINITY, INFINITY};
            ddB[q] = (v2f){INFINITY, INFINITY};
        }

        if (tid == 0) { sh.f.widxA[0] = 0; sh.f.widxB[0] = 0; }
        __syncthreads();

        // first selected point of each cloud: original index 0
        float lxA = sh.f.sxp[0], lyA = sh.f.syp[0], lzA = sh.f.szp[0];
        float lxB = pB[0], lyB = pB[1], lzB = pB[2];
        if (tid == 0) {
            size_t oA = (size_t)(bA * kM) * 3, oB = (size_t)(bB * kM) * 3;
            __hip_atomic_store(&stage[oA + 0], __float_as_uint(lxA),
                               __ATOMIC_RELAXED, __HIP_MEMORY_SCOPE_AGENT);
            __hip_atomic_store(&stage[oA + 1], __float_as_uint(lyA),
                               __ATOMIC_RELAXED, __HIP_MEMORY_SCOPE_AGENT);
            __hip_atomic_store(&stage[oA + 2], __float_as_uint(lzA),
                               __ATOMIC_RELAXED, __HIP_MEMORY_SCOPE_AGENT);
            __hip_atomic_store(&stage[oB + 0], __float_as_uint(lxB),
                               __ATOMIC_RELAXED, __HIP_MEMORY_SCOPE_AGENT);
            __hip_atomic_store(&stage[oB + 1], __float_as_uint(lyB),
                               __ATOMIC_RELAXED, __HIP_MEMORY_SCOPE_AGENT);
            __hip_atomic_store(&stage[oB + 2], __float_as_uint(lzB),
                               __ATOMIC_RELAXED, __HIP_MEMORY_SCOPE_AGENT);
            __hip_atomic_store(&prog[bA * 16], 1,
                               __ATOMIC_RELEASE, __HIP_MEMORY_SCOPE_AGENT);
            __hip_atomic_store(&prog[bB * 16], 1,
                               __ATOMIC_RELEASE, __HIP_MEMORY_SCOPE_AGENT);
        }

        for (int m = 1; m < kM; ++m) {
            unsigned int khiA, kloA, khiB, kloB;
            FPS_UPDATE_REDUCE(pxA, pyA, pzA, ddA, lxA, lyA, lzA, khiA, kloA, 0)
            FPS_UPDATE_REDUCE(pxB, pyB, pzB, ddB, lxB, lyB, lzB, khiB, kloB, 0)
            if (lane == 63) {
                sh.f.partA[m & 1][wave] =
                    ((unsigned long long)khiA << 32) | kloA;
                sh.f.partB[m & 1][wave] =
                    ((unsigned long long)khiB << 32) | kloB;
            }
            __syncthreads();

            // scan B first: its winner coords come from GLOBAL; the load
            // latency hides under cloud A's next update (independent).
            unsigned long long kb = sh.f.partB[m & 1][0];
#pragma unroll
            for (int w = 1; w < 4; ++w) {
                unsigned long long o = sh.f.partB[m & 1][w];
                if (o > kb) kb = o;
            }
            unsigned int wiB = ~(unsigned int)kb;
            lxB = pB[wiB * 3 + 0]; lyB = pB[wiB * 3 + 1]; lzB = pB[wiB * 3 + 2];

            unsigned long long ka = sh.f.partA[m & 1][0];
#pragma unroll
            for (int w = 1; w < 4; ++w) {
                unsigned long long o = sh.f.partA[m & 1][w];
                if (o > ka) ka = o;
            }
            unsigned int wiA = ~(unsigned int)ka;
            lxA = sh.f.sxp[wiA]; lyA = sh.f.syp[wiA]; lzA = sh.f.szp[wiA];

            if (tid == 0) {
                sh.f.widxA[m] = (unsigned short)wiA;
                sh.f.widxB[m] = (unsigned short)wiB;
            }

            // batched publish every 32 iterations (both clouds)
            if ((m & 31) == 31) {
                int m0 = m - 31;
                if (tid < 192) {
                    int s = tid / 3, comp = tid % 3;
                    int mm = m0 + (s & 31);
                    float v;
                    int cloud;
                    if (s < 32) {
                        unsigned int w2 = (mm == m) ? wiA
                                        : (unsigned int)sh.f.widxA[mm];
                        v = (comp == 0) ? sh.f.sxp[w2]
                          : (comp == 1) ? sh.f.syp[w2] : sh.f.szp[w2];
                        cloud = bA;
                    } else {
                        unsigned int w2 = (mm == m) ? wiB
                                        : (unsigned int)sh.f.widxB[mm];
                        v = pB[w2 * 3 + comp];
                        cloud = bB;
                    }
                    __hip_atomic_store(
                        &stage[(size_t)(cloud * kM + mm) * 3 + comp],
                        __float_as_uint(v),
                        __ATOMIC_RELAXED, __HIP_MEMORY_SCOPE_AGENT);
                }
                __syncthreads();   // drains publishing waves' stores
                if (tid == 0) {
                    __hip_atomic_store(&prog[bA * 16], m + 1,
                                       __ATOMIC_RELEASE, __HIP_MEMORY_SCOPE_AGENT);
                    __hip_atomic_store(&prog[bB * 16], m + 1,
                                       __ATOMIC_RELEASE, __HIP_MEMORY_SCOPE_AGENT);
                }
            }
            // ping-pong part[] + next barrier order the WAR hazard
        }
        __syncthreads();

        // cooperative centroid writeout (bit-exact copies of input coords)
#pragma unroll
        for (int q = 0; q < kM / 256; ++q) {
            int i = tid + q * 256;
            unsigned int wA = sh.f.widxA[i];
            size_t oA = (size_t)(bA * kM + i) * 3;
            cent_out[oA + 0] = sh.f.sxp[wA];
            cent_out[oA + 1] = sh.f.syp[wA];
            cent_out[oA + 2] = sh.f.szp[wA];
            unsigned int wB = sh.f.widxB[i];
            size_t oB = (size_t)(bB * kM + i) * 3;
            cent_out[oB + 0] = pB[wB * 3 + 0];
            cent_out[oB + 1] = pB[wB * 3 + 1];
            cent_out[oB + 2] = pB[wB * 3 + 2];
        }
        return;
    }

    // ======================= consumer role (G=4, MFMA; r14-proven) =========
    const int i = (int)blockIdx.x - 4;
    const int b = i & 7;                 // cloud-rotated dispatch
    const int cl0 = (i >> 3) * 4;        // first of 4 centroids

    // --- stage weights/biases (independent of fps progress) ---
    for (int idx = tid; idx < 64 * 64; idx += 256) {
        int n = idx & 63, kk = idx >> 6;
        sh.c.Wt1[n][kk] = (_Float16)((kk < 35) ? W1[kk * 64 + n] : 0.0f);
        sh.c.Wt2[n][kk] = (_Float16)W2[kk * 64 + n];
    }
    for (int idx = tid; idx < 64 * 128; idx += 256) {
        int n = idx & 127, kk = idx >> 7;
        sh.c.Wt3[n][kk] = (_Float16)W3[kk * 128 + n];
    }
    sh.c.bias[tid] = (tid < 64) ? b1[tid] : (tid < 128) ? b2[tid - 64]
                                                        : b3[tid - 128];

    // --- wait until fps has published all 4 centroids ---
    if (tid == 0) {
        int p;
        while ((p = __hip_atomic_load(&prog[b * 16], __ATOMIC_ACQUIRE,
                                      __HIP_MEMORY_SCOPE_AGENT)) < cl0 + 4) {
            if (cl0 + 4 - p > 128) __builtin_amdgcn_s_sleep(64);
            else                   __builtin_amdgcn_s_sleep(8);
        }
    }
    __syncthreads();   // orders weight staging + spin vs everything below

    // --- ball query: wave w owns centroid cl0+w (fp32-exact) ---
    const int c = b * kM + cl0 + wave;
    float cx = __uint_as_float(__hip_atomic_load(&stage[(size_t)c * 3 + 0],
                   __ATOMIC_RELAXED, __HIP_MEMORY_SCOPE_AGENT));
    float cy = __uint_as_float(__hip_atomic_load(&stage[(size_t)c * 3 + 1],
                   __ATOMIC_RELAXED, __HIP_MEMORY_SCOPE_AGENT));
    float cz = __uint_as_float(__hip_atomic_load(&stage[(size_t)c * 3 + 2],
                   __ATOMIC_RELAXED, __HIP_MEMORY_SCOPE_AGENT));
    {
        const float R2 = (float)(0.2 * 0.2);
        const float* pb = pos + (size_t)b * kP * 3;
        int cnt = 0;
        for (int p0 = 0; p0 < kP && cnt < kK; p0 += 64) {
            int idx = p0 + lane;
            float X = pb[idx * 3 + 0], Y = pb[idx * 3 + 1], Z = pb[idx * 3 + 2];
            float d2 = dist2(X, Y, Z, cx, cy, cz);
            bool in = d2 <= R2;
            unsigned long long mask = __ballot(in);
            int rank = __popcll(mask & ((1ull << lane) - 1ull));
            if (in && cnt + rank < kK) sh.c.s_nb[wave][cnt + rank] = idx;
            cnt = min(cnt + (int)__popcll(mask), kK);
        }
        if (lane == 0) { sh.c.s_cnt[wave] = cnt; batch_out[c] = (float)b; }
    }
    __syncthreads();   // fence: s_nb/s_cnt stores -> reads (compiler+HW)
    const int cntw = sh.c.s_cnt[wave];

    // --- gather: thread = row tid = (wave,lane); msg cols 0..63 (35 used) ---
    {
        int k = lane;
        if (k < cntw) {
            int n = sh.c.s_nb[wave][k];
            const float4* xr4 = (const float4*)(x + ((size_t)b * kP + n) * kF);
#pragma unroll
            for (int t = 0; t < 4; ++t) {
                float4 a4 = xr4[2 * t], c4 = xr4[2 * t + 1];
                h8 o = {(_Float16)a4.x, (_Float16)a4.y, (_Float16)a4.z,
                        (_Float16)a4.w, (_Float16)c4.x, (_Float16)c4.y,
                        (_Float16)c4.z, (_Float16)c4.w};
                *(h8*)&sh.c.A0[tid][t * 8] = o;
            }
            float dx = pos[((size_t)b * kP + n) * 3 + 0] - cx;
            float dy = pos[((size_t)b * kP + n) * 3 + 1] - cy;
            float dz = pos[((size_t)b * kP + n) * 3 + 2] - cz;
            h8 o4 = {(_Float16)dx, (_Float16)dy, (_Float16)dz,
                     (_Float16)0.f, (_Float16)0.f, (_Float16)0.f,
                     (_Float16)0.f, (_Float16)0.f};
            *(h8*)&sh.c.A0[tid][32] = o4;
            h8 z = {};
            *(h8*)&sh.c.A0[tid][40] = z;
            *(h8*)&sh.c.A0[tid][48] = z;
            *(h8*)&sh.c.A0[tid][56] = z;
        } else {
            h8 z = {};
#pragma unroll
            for (int t = 0; t < 8; ++t) *(h8*)&sh.c.A0[tid][t * 8] = z;
        }
    }
    __syncthreads();   // fence: A0 stores -> MFMA A-fragment reads

    const int m16 = lane & 15, quad = lane >> 4;

    // --- layer 1: A0(msg) x Wt1 -> A1(h1), N=64, K=64 (fp16 MFMA, f32 acc)
    {
        h8 bf[4][2];
#pragma unroll
        for (int nt = 0; nt < 4; ++nt)
#pragma unroll
            for (int kc = 0; kc < 2; ++kc)
                bf[nt][kc] = *(const h8*)&sh.c.Wt1[nt * 16 + m16][kc * 32 + quad * 8];
#pragma unroll
        for (int mt = 0; mt < 4; ++mt) {
            int m0 = wave * 64 + mt * 16;
            h8 a0 = *(const h8*)&sh.c.A0[m0 + m16][quad * 8];
            h8 a1 = *(const h8*)&sh.c.A0[m0 + m16][32 + quad * 8];
#pragma unroll
            for (int nt = 0; nt < 4; ++nt) {
                f4v acc = {0.f, 0.f, 0.f, 0.f};
                acc = __builtin_amdgcn_mfma_f32_16x16x32_f16(a0, bf[nt][0], acc, 0, 0, 0);
                acc = __builtin_amdgcn_mfma_f32_16x16x32_f16(a1, bf[nt][1], acc, 0, 0, 0);
                int n = nt * 16 + m16;
                float bb = sh.c.bias[n];
#pragma unroll
                for (int r = 0; r < 4; ++r)
                    sh.c.A1[m0 + quad * 4 + r][n] =
                        (_Float16)fmaxf(acc[r] + bb, 0.0f);
            }
        }
    }
    __syncthreads();   // fence: A1 stores -> layer-2 A-fragment reads

    // --- layer 2: A1(h1) x Wt2 -> A0(h2), N=64, K=64 ---
    {
        h8 bf[4][2];
#pragma unroll
        for (int nt = 0; nt < 4; ++nt)
#pragma unroll
            for (int kc = 0; kc < 2; ++kc)
                bf[nt][kc] = *(const h8*)&sh.c.Wt2[nt * 16 + m16][kc * 32 + quad * 8];
#pragma unroll
        for (int mt = 0; mt < 4; ++mt) {
            int m0 = wave * 64 + mt * 16;
            h8 a0 = *(const h8*)&sh.c.A1[m0 + m16][quad * 8];
            h8 a1 = *(const h8*)&sh.c.A1[m0 + m16][32 + quad * 8];
#pragma unroll
            for (int nt = 0; nt < 4; ++nt) {
                f4v acc = {0.f, 0.f, 0.f, 0.f};
                acc = __builtin_amdgcn_mfma_f32_16x16x32_f16(a0, bf[nt][0], acc, 0, 0, 0);
                acc = __builtin_amdgcn_mfma_f32_16x16x32_f16(a1, bf[nt][1], acc, 0, 0, 0);
                int n = nt * 16 + m16;
                float bb = sh.c.bias[64 + n];
#pragma unroll
                for (int r = 0; r < 4; ++r)
                    sh.c.A0[m0 + quad * 4 + r][n] =
                        (_Float16)fmaxf(acc[r] + bb, 0.0f);
            }
        }
    }
    __syncthreads();   // fence: A0(h2) stores -> layer-3 A-fragment reads

    // --- layer 3: A0(h2) x Wt3, N=128, K=64; fused relu+bias+masked max ---
    {
        h8 bf[8][2];
#pragma unroll
        for (int nt = 0; nt < 8; ++nt)
#pragma unroll
            for (int kc = 0; kc < 2; ++kc)
                bf[nt][kc] = *(const h8*)&sh.c.Wt3[nt * 16 + m16][kc * 32 + quad * 8];
        float best[8];
#pragma unroll
        for (int nt = 0; nt < 8; ++nt) best[nt] = -INFINITY;
#pragma unroll
        for (int mt = 0; mt < 4; ++mt) {
            int m0 = wave * 64 + mt * 16;
            h8 a0 = *(const h8*)&sh.c.A0[m0 + m16][quad * 8];
            h8 a1 = *(const h8*)&sh.c.A0[m0 + m16][32 + quad * 8];
#pragma unroll
            for (int nt = 0; nt < 8; ++nt) {
                f4v acc = {0.f, 0.f, 0.f, 0.f};
                acc = __builtin_amdgcn_mfma_f32_16x16x32_f16(a0, bf[nt][0], acc, 0, 0, 0);
                acc = __builtin_amdgcn_mfma_f32_16x16x32_f16(a1, bf[nt][1], acc, 0, 0, 0);
                int n = nt * 16 + m16;
                float bb = sh.c.bias[128 + n];
#pragma unroll
                for (int r = 0; r < 4; ++r) {
                    int krow = mt * 16 + quad * 4 + r;   // row within centroid
                    float v = fmaxf(acc[r] + bb, 0.0f);
                    if (krow < cntw) best[nt] = fmaxf(best[nt], v);
                }
            }
        }
#pragma unroll
        for (int nt = 0; nt < 8; ++nt)
            sh.c.red[wave][quad][nt * 16 + m16] = best[nt];
    }
    __syncthreads();

    // --- final: max over 4 quads, write feat_out ---
    {
        int w2 = tid >> 6, n = tid & 63;
#pragma unroll
        for (int h = 0; h < 2; ++h) {
            int n2 = n + h * 64;
            float o = fmaxf(fmaxf(sh.c.red[w2][0][n2], sh.c.red[w2][1][n2]),
                            fmaxf(sh.c.red[w2][2][n2], sh.c.red[w2][3][n2]));
            feat_out[(size_t)(b * kM + cl0 + w2) * kO + n2] = o;
        }
    }
}

// ---------------------------------------------------------------------------
extern "C" void kernel_launch(void* const* d_in, const int* in_sizes, int n_in,
                              void* d_out, int out_size, void* d_ws, size_t ws_size,
                              hipStream_t stream) {
    const float* pos = (const float*)d_in[0];
    // d_in[1] = batch (unused; implied by layout)
    const float* x  = (const float*)d_in[2];
    const float* W1 = (const float*)d_in[3];
    const float* b1 = (const float*)d_in[4];
    const float* W2 = (const float*)d_in[5];
    const float* b2 = (const float*)d_in[6];
    const float* W3 = (const float*)d_in[7];
    const float* b3 = (const float*)d_in[8];

    float* out = (float*)d_out;
    float* cent_out  = out;                                   // [B*M, 3]
    float* feat_out  = out + (size_t)kB * kM * 3;             // [B*M, 128]
    float* batch_out = out + (size_t)kB * kM * (3 + kO);      // [B*M]

    char* ws = (char*)d_ws;
    int* prog           = (int*)ws;                           // 128 ints (strided)
    unsigned int* stage = (unsigned int*)(ws + 512);          // B*M*3 uints

    init_kernel<<<1, 128, 0, stream>>>(prog);
    mega_kernel<<<4 + (kB * kM) / 4, 256, 0, stream>>>(
        pos, x, W1, b1, W2, b2, W3, b3, stage, prog,
        cent_out, feat_out, batch_out);
}

// Round 17
// 2153.587 us; speedup vs baseline: 2.2404x; 2.2404x over previous
//
#include <hip/hip_runtime.h>
#include <stdint.h>
#include <math.h>

// Problem constants (from reference)
constexpr int kB = 8;      // clouds
constexpr int kP = 8192;   // points per cloud
constexpr int kF = 32;     // feature dim
constexpr int kM = 2048;   // centroids per cloud (P * 0.25)
constexpr int kK = 64;     // max neighbors
constexpr int kO = 128;    // output dim

typedef float v2f __attribute__((ext_vector_type(2)));
typedef _Float16 h8 __attribute__((ext_vector_type(8)));
typedef float f4v __attribute__((ext_vector_type(4)));

// Exact-f32 squared distance matching numpy: square elementwise, then
// sequential sum ((dx2+dy2)+dz2). contract(off) forbids fma fusion so this
// matches numpy bit-for-bit regardless of -ffp-contract=fast default.
__device__ __forceinline__ float dist2(float ax, float ay, float az,
                                       float bx, float by, float bz) {
#pragma clang fp contract(off)
    float dx = ax - bx, dy = ay - by, dz = az - bz;
    return (dx * dx + dy * dy) + dz * dz;
}

// One DPP step of a u64 (hi,lo) max-reduce. CTRL must be an immediate ->
// template parameter. bound_ctrl=true: invalid source lanes read 0, and
// (0,0) never wins because all real keys have klo = ~idx != 0.
template <int CTRL>
__device__ __forceinline__ void dpp_max_step(unsigned int& khi, unsigned int& klo) {
    unsigned int ohi = (unsigned int)__builtin_amdgcn_update_dpp(
        0, (int)khi, CTRL, 0xf, 0xf, true);
    unsigned int olo = (unsigned int)__builtin_amdgcn_update_dpp(
        0, (int)klo, CTRL, 0xf, 0xf, true);
    bool take = (ohi > khi) || (ohi == khi && olo > klo);
    khi = take ? ohi : khi;
    klo = take ? olo : klo;
}

// Zero the progress flags (d_ws is poisoned 0xAA before every launch).
__global__ void init_kernel(int* __restrict__ prog) {
    if (threadIdx.x < 128) prog[threadIdx.x] = 0;
}

// Role-union LDS. fps: big coord arrays (~100 KB). consumer: fp16 MFMA
// tiles + transposed fp16 weights (~121 KB). 1 block/CU either way.
union SharedU {
    struct {
        float sxp[kP], syp[kP], szp[kP];       // SoA cloud copy
        unsigned short widx[kM];               // winner index per iteration
        unsigned long long part[2][4];         // ping-pong wave partials
    } f;
    struct {
        _Float16 A0[256][72];                  // msg (cols 0..63), reused as h2
        _Float16 A1[256][72];                  // h1
        _Float16 Wt1[64][72];                  // W1^T [n][k], k>=35 zero
        _Float16 Wt2[64][72];                  // W2^T [n][k]
        _Float16 Wt3[128][72];                 // W3^T [n][k]
        float bias[256];                       // b1 | b2 | b3
        float red[4][4][128];                  // [centroid][quad][col]
        int   s_nb[4][kK];
        int   s_cnt[4];
    } c;
};

// ---------------------------------------------------------------------------
// Mega-kernel: producer/consumer overlap. (r14 configuration — empirical
// best: fps ~2065 µs serial critical path, consumers fully hidden.)
//  blocks 0..7    : FPS for cloud b (bit-exact). Zero global stores in the
//                   per-iteration loop; batch publish every 32 iters.
//  blocks 8..4103 : 4 consecutive centroids of cloud b = i&7.
//                   Stage weights -> spin on prog[b] -> per-wave ball query
//                   -> per-wave gather -> per-wave fp16 MFMA MLP (fp32 acc)
//                   -> fused masked max -> cross-quad reduce -> feat_out.
// __syncthreads() at EVERY consumer phase boundary (r13's crash: compiler
// hoisted the loop-invariant s_cnt LDS load above the ball-query stores).
// ---------------------------------------------------------------------------
__global__ __launch_bounds__(256, 1) void mega_kernel(
    const float* __restrict__ pos, const float* __restrict__ x,
    const float* __restrict__ W1, const float* __restrict__ b1,
    const float* __restrict__ W2, const float* __restrict__ b2,
    const float* __restrict__ W3, const float* __restrict__ b3,
    unsigned int* __restrict__ stage, int* __restrict__ prog,
    float* __restrict__ cent_out, float* __restrict__ feat_out,
    float* __restrict__ batch_out) {
    __shared__ SharedU sh;

    const int tid = threadIdx.x;
    const int wave = tid >> 6, lane = tid & 63;

    if (blockIdx.x < (unsigned)kB) {
        // ======================= FPS role =======================
        const int b = blockIdx.x;
        const float* pb = pos + (size_t)b * kP * 3;

        v2f px2[16], py2[16], pz2[16], dd2[16];
#pragma unroll
        for (int q = 0; q < 32; ++q) {
            int i = tid + q * 256;
            float X = pb[i * 3 + 0];
            float Y = pb[i * 3 + 1];
            float Z = pb[i * 3 + 2];
            sh.f.sxp[i] = X; sh.f.syp[i] = Y; sh.f.szp[i] = Z;
            if (q & 1) { px2[q >> 1].y = X; py2[q >> 1].y = Y; pz2[q >> 1].y = Z; }
            else       { px2[q >> 1].x = X; py2[q >> 1].x = Y; pz2[q >> 1].x = Z; }
        }
#pragma unroll
        for (int q = 0; q < 16; ++q) dd2[q] = (v2f){INFINITY, INFINITY};

        if (tid == 0) sh.f.widx[0] = 0;
        __syncthreads();

        float lx = sh.f.sxp[0], ly = sh.f.syp[0], lz = sh.f.szp[0];
        if (tid == 0) {
            size_t o = (size_t)(b * kM) * 3;
            __hip_atomic_store(&stage[o + 0], __float_as_uint(lx),
                               __ATOMIC_RELAXED, __HIP_MEMORY_SCOPE_AGENT);
            __hip_atomic_store(&stage[o + 1], __float_as_uint(ly),
                               __ATOMIC_RELAXED, __HIP_MEMORY_SCOPE_AGENT);
            __hip_atomic_store(&stage[o + 2], __float_as_uint(lz),
                               __ATOMIC_RELAXED, __HIP_MEMORY_SCOPE_AGENT);
            __hip_atomic_store(&prog[b * 16], 1,
                               __ATOMIC_RELEASE, __HIP_MEMORY_SCOPE_AGENT);
        }

        for (int m = 1; m < kM; ++m) {
            v2f lxv = {lx, lx}, lyv = {ly, ly}, lzv = {lz, lz};
#pragma unroll
            for (int q = 0; q < 16; ++q) {
#pragma clang fp contract(off)
                v2f dx = px2[q] - lxv;
                v2f dy = py2[q] - lyv;
                v2f dz = pz2[q] - lzv;
                v2f d2 = (dx * dx + dy * dy) + dz * dz;
                dd2[q].x = fminf(dd2[q].x, d2.x);
                dd2[q].y = fminf(dd2[q].y, d2.y);
            }

            v2f t0 = {fmaxf(dd2[0].x, dd2[0].y), fmaxf(dd2[1].x, dd2[1].y)};
            v2f t1 = {fmaxf(dd2[2].x, dd2[2].y), fmaxf(dd2[3].x, dd2[3].y)};
            v2f t2 = {fmaxf(dd2[4].x, dd2[4].y), fmaxf(dd2[5].x, dd2[5].y)};
            v2f t3 = {fmaxf(dd2[6].x, dd2[6].y), fmaxf(dd2[7].x, dd2[7].y)};
            v2f t4 = {fmaxf(dd2[8].x, dd2[8].y), fmaxf(dd2[9].x, dd2[9].y)};
            v2f t5 = {fmaxf(dd2[10].x, dd2[10].y), fmaxf(dd2[11].x, dd2[11].y)};
            v2f t6 = {fmaxf(dd2[12].x, dd2[12].y), fmaxf(dd2[13].x, dd2[13].y)};
            v2f t7 = {fmaxf(dd2[14].x, dd2[14].y), fmaxf(dd2[15].x, dd2[15].y)};
            float u0 = fmaxf(fmaxf(t0.x, t0.y), fmaxf(t1.x, t1.y));
            float u1 = fmaxf(fmaxf(t2.x, t2.y), fmaxf(t3.x, t3.y));
            float u2 = fmaxf(fmaxf(t4.x, t4.y), fmaxf(t5.x, t5.y));
            float u3 = fmaxf(fmaxf(t6.x, t6.y), fmaxf(t7.x, t7.y));
            float bv = fmaxf(fmaxf(u0, u1), fmaxf(u2, u3));

            int lqs[4];
#pragma unroll
            for (int g = 0; g < 4; ++g) {
                int t = 64;
#pragma unroll
                for (int s = 7; s >= 0; --s) {
                    int sl = g * 8 + s;
                    float v = (sl & 1) ? dd2[sl >> 1].y : dd2[sl >> 1].x;
                    t = (v == bv) ? sl : t;
                }
                lqs[g] = t;
            }
            int bq = lqs[3];
            bq = (lqs[2] < 64) ? lqs[2] : bq;
            bq = (lqs[1] < 64) ? lqs[1] : bq;
            bq = (lqs[0] < 64) ? lqs[0] : bq;

            unsigned int bidx = (unsigned int)(tid + bq * 256);
            unsigned int khi = __float_as_uint(bv);
            unsigned int klo = (unsigned int)(~bidx);

            dpp_max_step<0x111>(khi, klo);
            dpp_max_step<0x112>(khi, klo);
            dpp_max_step<0x114>(khi, klo);
            dpp_max_step<0x118>(khi, klo);
            dpp_max_step<0x142>(khi, klo);
            dpp_max_step<0x143>(khi, klo);
            if (lane == 63)
                sh.f.part[m & 1][wave] = ((unsigned long long)khi << 32) | klo;
            __syncthreads();

            unsigned long long k = sh.f.part[m & 1][0];
#pragma unroll
            for (int w = 1; w < 4; ++w) {
                unsigned long long o = sh.f.part[m & 1][w];
                if (o > k) k = o;
            }
            unsigned int wi = ~(unsigned int)k;
            lx = sh.f.sxp[wi]; ly = sh.f.syp[wi]; lz = sh.f.szp[wi];
            if (tid == 0) sh.f.widx[m] = (unsigned short)wi;

            if ((m & 31) == 31) {
                int m0 = m - 31;
                if (tid < 96) {
                    int mm = m0 + tid / 3;
                    int comp = tid % 3;
                    unsigned int w2 = (mm == m) ? wi
                                                : (unsigned int)sh.f.widx[mm];
                    float v = (comp == 0) ? sh.f.sxp[w2]
                            : (comp == 1) ? sh.f.syp[w2] : sh.f.szp[w2];
                    __hip_atomic_store(&stage[(size_t)(b * kM + mm) * 3 + comp],
                                       __float_as_uint(v),
                                       __ATOMIC_RELAXED, __HIP_MEMORY_SCOPE_AGENT);
                }
                __syncthreads();
                if (tid == 0)
                    __hip_atomic_store(&prog[b * 16], m + 1,
                                       __ATOMIC_RELEASE, __HIP_MEMORY_SCOPE_AGENT);
            }
        }
        __syncthreads();

#pragma unroll
        for (int q = 0; q < kM / 256; ++q) {
            int i = tid + q * 256;
            unsigned int wi = sh.f.widx[i];
            size_t o = (size_t)(b * kM + i) * 3;
            cent_out[o + 0] = sh.f.sxp[wi];
            cent_out[o + 1] = sh.f.syp[wi];
            cent_out[o + 2] = sh.f.szp[wi];
        }
        return;
    }

    // ======================= consumer role (G=4, MFMA) =====================
    const int i = (int)blockIdx.x - kB;
    const int b = i & 7;                 // cloud-rotated dispatch
    const int cl0 = (i >> 3) * 4;        // first of 4 centroids

    // --- stage weights/biases (independent of fps progress) ---
    for (int idx = tid; idx < 64 * 64; idx += 256) {
        int n = idx & 63, kk = idx >> 6;
        sh.c.Wt1[n][kk] = (_Float16)((kk < 35) ? W1[kk * 64 + n] : 0.0f);
        sh.c.Wt2[n][kk] = (_Float16)W2[kk * 64 + n];
    }
    for (int idx = tid; idx < 64 * 128; idx += 256) {
        int n = idx & 127, kk = idx >> 7;
        sh.c.Wt3[n][kk] = (_Float16)W3[kk * 128 + n];
    }
    sh.c.bias[tid] = (tid < 64) ? b1[tid] : (tid < 128) ? b2[tid - 64]
                                                        : b3[tid - 128];

    // --- wait until fps has published all 4 centroids ---
    if (tid == 0) {
        int p;
        while ((p = __hip_atomic_load(&prog[b * 16], __ATOMIC_ACQUIRE,
                                      __HIP_MEMORY_SCOPE_AGENT)) < cl0 + 4) {
            if (cl0 + 4 - p > 128) __builtin_amdgcn_s_sleep(64);
            else                   __builtin_amdgcn_s_sleep(8);
        }
    }
    __syncthreads();   // orders weight staging + spin vs everything below

    // --- ball query: wave w owns centroid cl0+w (fp32-exact) ---
    const int c = b * kM + cl0 + wave;
    float cx = __uint_as_float(__hip_atomic_load(&stage[(size_t)c * 3 + 0],
                   __ATOMIC_RELAXED, __HIP_MEMORY_SCOPE_AGENT));
    float cy = __uint_as_float(__hip_atomic_load(&stage[(size_t)c * 3 + 1],
                   __ATOMIC_RELAXED, __HIP_MEMORY_SCOPE_AGENT));
    float cz = __uint_as_float(__hip_atomic_load(&stage[(size_t)c * 3 + 2],
                   __ATOMIC_RELAXED, __HIP_MEMORY_SCOPE_AGENT));
    {
        const float R2 = (float)(0.2 * 0.2);
        const float* pb = pos + (size_t)b * kP * 3;
        int cnt = 0;
        for (int p0 = 0; p0 < kP && cnt < kK; p0 += 64) {
            int idx = p0 + lane;
            float X = pb[idx * 3 + 0], Y = pb[idx * 3 + 1], Z = pb[idx * 3 + 2];
            float d2 = dist2(X, Y, Z, cx, cy, cz);
            bool in = d2 <= R2;
            unsigned long long mask = __ballot(in);
            int rank = __popcll(mask & ((1ull << lane) - 1ull));
            if (in && cnt + rank < kK) sh.c.s_nb[wave][cnt + rank] = idx;
            cnt = min(cnt + (int)__popcll(mask), kK);
        }
        if (lane == 0) { sh.c.s_cnt[wave] = cnt; batch_out[c] = (float)b; }
    }
    __syncthreads();   // fence: s_nb/s_cnt stores -> reads (compiler+HW)
    const int cntw = sh.c.s_cnt[wave];

    // --- gather: thread = row tid = (wave,lane); msg cols 0..63 (35 used) ---
    {
        int k = lane;
        if (k < cntw) {
            int n = sh.c.s_nb[wave][k];
            const float4* xr4 = (const float4*)(x + ((size_t)b * kP + n) * kF);
#pragma unroll
            for (int t = 0; t < 4; ++t) {
                float4 a4 = xr4[2 * t], c4 = xr4[2 * t + 1];
                h8 o = {(_Float16)a4.x, (_Float16)a4.y, (_Float16)a4.z,
                        (_Float16)a4.w, (_Float16)c4.x, (_Float16)c4.y,
                        (_Float16)c4.z, (_Float16)c4.w};
                *(h8*)&sh.c.A0[tid][t * 8] = o;
            }
            float dx = pos[((size_t)b * kP + n) * 3 + 0] - cx;
            float dy = pos[((size_t)b * kP + n) * 3 + 1] - cy;
            float dz = pos[((size_t)b * kP + n) * 3 + 2] - cz;
            h8 o4 = {(_Float16)dx, (_Float16)dy, (_Float16)dz,
                     (_Float16)0.f, (_Float16)0.f, (_Float16)0.f,
                     (_Float16)0.f, (_Float16)0.f};
            *(h8*)&sh.c.A0[tid][32] = o4;
            h8 z = {};
            *(h8*)&sh.c.A0[tid][40] = z;
            *(h8*)&sh.c.A0[tid][48] = z;
            *(h8*)&sh.c.A0[tid][56] = z;
        } else {
            h8 z = {};
#pragma unroll
            for (int t = 0; t < 8; ++t) *(h8*)&sh.c.A0[tid][t * 8] = z;
        }
    }
    __syncthreads();   // fence: A0 stores -> MFMA A-fragment reads

    const int m16 = lane & 15, quad = lane >> 4;

    // --- layer 1: A0(msg) x Wt1 -> A1(h1), N=64, K=64 (fp16 MFMA, f32 acc)
    {
        h8 bf[4][2];
#pragma unroll
        for (int nt = 0; nt < 4; ++nt)
#pragma unroll
            for (int kc = 0; kc < 2; ++kc)
                bf[nt][kc] = *(const h8*)&sh.c.Wt1[nt * 16 + m16][kc * 32 + quad * 8];
#pragma unroll
        for (int mt = 0; mt < 4; ++mt) {
            int m0 = wave * 64 + mt * 16;
            h8 a0 = *(const h8*)&sh.c.A0[m0 + m16][quad * 8];
            h8 a1 = *(const h8*)&sh.c.A0[m0 + m16][32 + quad * 8];
#pragma unroll
            for (int nt = 0; nt < 4; ++nt) {
                f4v acc = {0.f, 0.f, 0.f, 0.f};
                acc = __builtin_amdgcn_mfma_f32_16x16x32_f16(a0, bf[nt][0], acc, 0, 0, 0);
                acc = __builtin_amdgcn_mfma_f32_16x16x32_f16(a1, bf[nt][1], acc, 0, 0, 0);
                int n = nt * 16 + m16;
                float bb = sh.c.bias[n];
#pragma unroll
                for (int r = 0; r < 4; ++r)
                    sh.c.A1[m0 + quad * 4 + r][n] =
                        (_Float16)fmaxf(acc[r] + bb, 0.0f);
            }
        }
    }
    __syncthreads();   // fence: A1 stores -> layer-2 A-fragment reads

    // --- layer 2: A1(h1) x Wt2 -> A0(h2), N=64, K=64 ---
    {
        h8 bf[4][2];
#pragma unroll
        for (int nt = 0; nt < 4; ++nt)
#pragma unroll
            for (int kc = 0; kc < 2; ++kc)
                bf[nt][kc] = *(const h8*)&sh.c.Wt2[nt * 16 + m16][kc * 32 + quad * 8];
#pragma unroll
        for (int mt = 0; mt < 4; ++mt) {
            int m0 = wave * 64 + mt * 16;
            h8 a0 = *(const h8*)&sh.c.A1[m0 + m16][quad * 8];
            h8 a1 = *(const h8*)&sh.c.A1[m0 + m16][32 + quad * 8];
#pragma unroll
            for (int nt = 0; nt < 4; ++nt) {
                f4v acc = {0.f, 0.f, 0.f, 0.f};
                acc = __builtin_amdgcn_mfma_f32_16x16x32_f16(a0, bf[nt][0], acc, 0, 0, 0);
                acc = __builtin_amdgcn_mfma_f32_16x16x32_f16(a1, bf[nt][1], acc, 0, 0, 0);
                int n = nt * 16 + m16;
                float bb = sh.c.bias[64 + n];
#pragma unroll
                for (int r = 0; r < 4; ++r)
                    sh.c.A0[m0 + quad * 4 + r][n] =
                        (_Float16)fmaxf(acc[r] + bb, 0.0f);
            }
        }
    }
    __syncthreads();   // fence: A0(h2) stores -> layer-3 A-fragment reads

    // --- layer 3: A0(h2) x Wt3, N=128, K=64; fused relu+bias+masked max ---
    {
        h8 bf[8][2];
#pragma unroll
        for (int nt = 0; nt < 8; ++nt)
#pragma unroll
            for (int kc = 0; kc < 2; ++kc)
                bf[nt][kc] = *(const h8*)&sh.c.Wt3[nt * 16 + m16][kc * 32 + quad * 8];
        float best[8];
#pragma unroll
        for (int nt = 0; nt < 8; ++nt) best[nt] = -INFINITY;
#pragma unroll
        for (int mt = 0; mt < 4; ++mt) {
            int m0 = wave * 64 + mt * 16;
            h8 a0 = *(const h8*)&sh.c.A0[m0 + m16][quad * 8];
            h8 a1 = *(const h8*)&sh.c.A0[m0 + m16][32 + quad * 8];
#pragma unroll
            for (int nt = 0; nt < 8; ++nt) {
                f4v acc = {0.f, 0.f, 0.f, 0.f};
                acc = __builtin_amdgcn_mfma_f32_16x16x32_f16(a0, bf[nt][0], acc, 0, 0, 0);
                acc = __builtin_amdgcn_mfma_f32_16x16x32_f16(a1, bf[nt][1], acc, 0, 0, 0);
                int n = nt * 16 + m16;
                float bb = sh.c.bias[128 + n];
#pragma unroll
                for (int r = 0; r < 4; ++r) {
                    int krow = mt * 16 + quad * 4 + r;   // row within centroid
                    float v = fmaxf(acc[r] + bb, 0.0f);
                    if (krow < cntw) best[nt] = fmaxf(best[nt], v);
                }
            }
        }
#pragma unroll
        for (int nt = 0; nt < 8; ++nt)
            sh.c.red[wave][quad][nt * 16 + m16] = best[nt];
    }
    __syncthreads();

    // --- final: max over 4 quads, write feat_out ---
    {
        int w2 = tid >> 6, n = tid & 63;
#pragma unroll
        for (int h = 0; h < 2; ++h) {
            int n2 = n + h * 64;
            float o = fmaxf(fmaxf(sh.c.red[w2][0][n2], sh.c.red[w2][1][n2]),
                            fmaxf(sh.c.red[w2][2][n2], sh.c.red[w2][3][n2]));
            feat_out[(size_t)(b * kM + cl0 + w2) * kO + n2] = o;
        }
    }
}

// ---------------------------------------------------------------------------
extern "C" void kernel_launch(void* const* d_in, const int* in_sizes, int n_in,
                              void* d_out, int out_size, void* d_ws, size_t ws_size,
                              hipStream_t stream) {
    const float* pos = (const float*)d_in[0];
    // d_in[1] = batch (unused; implied by layout)
    const float* x  = (const float*)d_in[2];
    const float* W1 = (const float*)d_in[3];
    const float* b1 = (const float*)d_in[4];
    const float* W2 = (const float*)d_in[5];
    const float* b2 = (const float*)d_in[6];
    const float* W3 = (const float*)d_in[7];
    const float* b3 = (const float*)d_in[8];

    float* out = (float*)d_out;
    float* cent_out  = out;                                   // [B*M, 3]
    float* feat_out  = out + (size_t)kB * kM * 3;             // [B*M, 128]
    float* batch_out = out + (size_t)kB * kM * (3 + kO);      // [B*M]

    char* ws = (char*)d_ws;
    int* prog           = (int*)ws;                           // 128 ints (strided)
    unsigned int* stage = (unsigned int*)(ws + 512);          // B*M*3 uints

    init_kernel<<<1, 128, 0, stream>>>(prog);
    mega_kernel<<<kB + (kB * kM) / 4, 256, 0, stream>>>(
        pos, x, W1, b1, W2, b2, W3, b3, stage, prog,
        cent_out, feat_out, batch_out);
}